// Round 13
// baseline (2661.736 us; speedup 1.0000x reference)
//
#include <hip/hip_runtime.h>
#include <math.h>

// Problem constants
#define B_ 32
#define T_ 512
#define N_ 512
#define D_ 4
#define H_ 2048
#define C_ 128

typedef __attribute__((ext_vector_type(8))) short short8_t;
typedef __attribute__((ext_vector_type(4))) float float4_t;

// inline-asm MFMA: A from AGPR ("a") or VGPR ("v"), B from VGPR, acc in VGPR.
#define MFMA_A(ACC, AF, BF) \
    asm("v_mfma_f32_16x16x32_bf16 %0, %1, %2, %0" : "+v"(ACC) : "a"(AF), "v"(BF))
#define MFMA_V(ACC, AF, BF) \
    asm("v_mfma_f32_16x16x32_bf16 %0, %1, %2, %0" : "+v"(ACC) : "v"(AF), "v"(BF))

// ---------------- helpers ----------------
__device__ __forceinline__ unsigned f2bf(float x) {
    unsigned u = __float_as_uint(x);
    return (u + 0x7fffu + ((u >> 16) & 1u)) >> 16;
}
__device__ __forceinline__ float bf2f(unsigned u) {
    return __uint_as_float(u << 16);
}
#define INV2PI 0.15915494309189535f
__device__ __forceinline__ float sin_hw(float x) {
    float r = x * INV2PI;
    r -= floorf(r);
    return __builtin_amdgcn_sinf(r);
}
__device__ __forceinline__ float cos_hw(float x) {
    float r = x * INV2PI;
    r -= floorf(r);
    return __builtin_amdgcn_cosf(r);
}

// ---------------- f32 -> bf16 straight convert (packed pairs) ----------------
__global__ __launch_bounds__(256) void cvt_bf16_kernel(
    const float* __restrict__ in, unsigned* __restrict__ out, int n2) {
    int i = blockIdx.x * 256 + threadIdx.x;
    if (i < n2) out[i] = f2bf(in[2 * i]) | (f2bf(in[2 * i + 1]) << 16);
}

// ---------------- f32 [R,C] -> bf16 [C,R] transpose-convert ----------------
__global__ __launch_bounds__(256) void cvt_T_kernel(
    const float* __restrict__ in, unsigned short* __restrict__ out, int R, int C) {
    __shared__ float tl[32][33];
    const int tr = blockIdx.y * 32, tc = blockIdx.x * 32;
    const int a = threadIdx.x >> 3, b4 = (threadIdx.x & 7) * 4;
    float4 v = *(const float4*)(in + (size_t)(tr + a) * C + tc + b4);
    tl[a][b4] = v.x; tl[a][b4 + 1] = v.y; tl[a][b4 + 2] = v.z; tl[a][b4 + 3] = v.w;
    __syncthreads();
    unsigned* o32 = (unsigned*)out;
    size_t base = ((size_t)(tc + a) * R + tr + b4) >> 1;
    o32[base]     = f2bf(tl[b4][a])     | (f2bf(tl[b4 + 1][a]) << 16);
    o32[base + 1] = f2bf(tl[b4 + 2][a]) | (f2bf(tl[b4 + 3][a]) << 16);
}

// ---------------- bf16 MFMA GEMM: C[M,N] = A[M,K] @ BT[N,K]^T + bias ----------------
// 128x128 tile, BK=64, 256 threads (4 waves, 2x2), 4x4 frags of 16x16x32.
// EPI: 0 = f32 out, 1 = bf16 out, 2 = mask (sigmoid, scale featb rows in place).
// AREMAP: A row (b,t) read from (b, max(0,t-2)).
template <int EPI, bool AREMAP>
__global__ __launch_bounds__(256) void gemm_bf16(
    const unsigned short* __restrict__ A, const unsigned short* __restrict__ BT,
    const float* __restrict__ bias, void* __restrict__ Cout,
    int M, int N, int K) {
    __shared__ unsigned short Al[128 * 72];
    __shared__ unsigned short Bl[128 * 72];
    const int tid = threadIdx.x;
    const int wid = tid >> 6, l = tid & 63;
    const int c = l & 15, q = l >> 4;
    const int wr = wid >> 1, wc = wid & 1;
    const int m0 = blockIdx.y * 128, n0 = blockIdx.x * 128;
    float4_t acc[4][4];
#pragma unroll
    for (int i = 0; i < 4; ++i)
#pragma unroll
        for (int j = 0; j < 4; ++j) acc[i][j] = (float4_t){0.f, 0.f, 0.f, 0.f};

    const int sr = tid >> 1, sh = tid & 1;
    size_t a_row = (size_t)(m0 + sr);
    if (AREMAP) {
        int tt = (m0 + sr) & 511;
        a_row = (size_t)(((m0 + sr) & ~511) | (tt < 2 ? 0 : tt - 2));
    }
    const unsigned short* ag = A + a_row * K + sh * 32;
    const unsigned short* bg = BT + (size_t)(n0 + sr) * K + sh * 32;
    unsigned short* aw = Al + sr * 72 + sh * 32;
    unsigned short* bw = Bl + sr * 72 + sh * 32;

    for (int k0 = 0; k0 < K; k0 += 64) {
        uint4 av0 = *(const uint4*)(ag);
        uint4 av1 = *(const uint4*)(ag + 8);
        uint4 av2 = *(const uint4*)(ag + 16);
        uint4 av3 = *(const uint4*)(ag + 24);
        uint4 bv0 = *(const uint4*)(bg);
        uint4 bv1 = *(const uint4*)(bg + 8);
        uint4 bv2 = *(const uint4*)(bg + 16);
        uint4 bv3 = *(const uint4*)(bg + 24);
        __syncthreads();  // prior frag reads complete
        *(uint4*)(aw) = av0; *(uint4*)(aw + 8) = av1;
        *(uint4*)(aw + 16) = av2; *(uint4*)(aw + 24) = av3;
        *(uint4*)(bw) = bv0; *(uint4*)(bw + 8) = bv1;
        *(uint4*)(bw + 16) = bv2; *(uint4*)(bw + 24) = bv3;
        __syncthreads();
#pragma unroll
        for (int kk = 0; kk < 2; ++kk) {
            short8_t af[4], bf[4];
#pragma unroll
            for (int mt = 0; mt < 4; ++mt)
                af[mt] = *(const short8_t*)(Al + (wr * 64 + mt * 16 + c) * 72 + kk * 32 + q * 8);
#pragma unroll
            for (int nt = 0; nt < 4; ++nt)
                bf[nt] = *(const short8_t*)(Bl + (wc * 64 + nt * 16 + c) * 72 + kk * 32 + q * 8);
#pragma unroll
            for (int mt = 0; mt < 4; ++mt)
#pragma unroll
                for (int nt = 0; nt < 4; ++nt)
                    acc[mt][nt] = __builtin_amdgcn_mfma_f32_16x16x32_bf16(
                        af[mt], bf[nt], acc[mt][nt], 0, 0, 0);
        }
        ag += 64; bg += 64;
    }

#pragma unroll
    for (int mt = 0; mt < 4; ++mt) {
        int row = m0 + wr * 64 + mt * 16 + q * 4;
#pragma unroll
        for (int nt = 0; nt < 4; ++nt) {
            int col = n0 + wc * 64 + nt * 16 + c;
            float bs = bias[col];
            if (EPI == 0) {
                float* Cf = (float*)Cout;
#pragma unroll
                for (int r = 0; r < 4; ++r)
                    Cf[(size_t)(row + r) * N + col] = acc[mt][nt][r] + bs;
            } else if (EPI == 1) {
                unsigned short* Cb = (unsigned short*)Cout;
#pragma unroll
                for (int r = 0; r < 4; ++r)
                    Cb[(size_t)(row + r) * N + col] = (unsigned short)f2bf(acc[mt][nt][r] + bs);
            } else {
                unsigned short* Fb = (unsigned short*)Cout;
#pragma unroll
                for (int r = 0; r < 4; ++r) {
                    float s = 1.f / (1.f + __expf(-(acc[mt][nt][r] + bs)));
                    unsigned short* fp = Fb + (size_t)(row + r) * 2048 + col * 4;
                    unsigned u0 = *(const unsigned*)fp;
                    unsigned u1 = *(const unsigned*)(fp + 2);
                    float f0 = bf2f(u0 & 0xffffu) * s;
                    float f1 = __uint_as_float(u0 & 0xffff0000u) * s;
                    float f2 = bf2f(u1 & 0xffffu) * s;
                    float f3 = __uint_as_float(u1 & 0xffff0000u) * s;
                    *(unsigned*)fp = f2bf(f0) | (f2bf(f1) << 16);
                    *(unsigned*)(fp + 2) = f2bf(f2) | (f2bf(f3) << 16);
                }
            }
        }
    }
}

// ---------------- LayerNorm + LeakyReLU over bf16 rows of H=2048, in place ----------------
__device__ __forceinline__ float block_sum256(float v, float* red) {
#pragma unroll
    for (int o = 32; o > 0; o >>= 1) v += __shfl_down(v, o, 64);
    int w = threadIdx.x >> 6;
    if ((threadIdx.x & 63) == 0) red[w] = v;
    __syncthreads();
    float r = red[0] + red[1] + red[2] + red[3];
    __syncthreads();
    return r;
}

__global__ __launch_bounds__(256) void ln_leaky_kernel(
    unsigned short* __restrict__ Z, const float* __restrict__ gam,
    const float* __restrict__ bet) {
    __shared__ float red[4];
    unsigned short* zr = Z + (size_t)blockIdx.x * H_;
    const int tid = threadIdx.x;
    float v[8];
    float s = 0.f;
#pragma unroll
    for (int i = 0; i < 8; ++i) { v[i] = bf2f((unsigned)zr[tid + i * 256]); s += v[i]; }
    s = block_sum256(s, red);
    float mu = s * (1.f / H_);
    float qq = 0.f;
#pragma unroll
    for (int i = 0; i < 8; ++i) { float dd = v[i] - mu; qq += dd * dd; }
    qq = block_sum256(qq, red);
    float rs = rsqrtf(qq * (1.f / H_) + 1e-5f);
#pragma unroll
    for (int i = 0; i < 8; ++i) {
        int cc = tid + i * 256;
        float y = (v[i] - mu) * rs * gam[cc] + bet[cc];
        zr[cc] = (unsigned short)f2bf(y > 0.f ? y : 0.1f * y);
    }
}

// ---------------- theta-scan v10: r12 + sc pinned in the AGPR file ----------------
// 32 blocks x 512 threads, one batch per block (r12 separable layout).
// NEW: tiles 0,1,3 (rows w*16, 128+w*16, 384+w*16) live in 192 AGPRs via inline-asm
// MFMA "a"-constraint operands — the allocator cannot rematerialize them, and the
// MFMA reads A directly from AGPR (ISA §10) => zero per-step sc memory traffic for
// 3 of 4 tiles. Tile 2 stays LDS (waves 0-6) / L2-stream (wave 7).
#define SCAN_LDS_BYTES 149760
// LDS: sc_lds [112][520]u16 @0 (116480) ; XT0 @116480 (16640) ; XT1 @133120 (16640)

__global__ __launch_bounds__(512) __attribute__((amdgpu_waves_per_eu(2, 2)))
void scan_kernel(
    const unsigned short* __restrict__ scb,  // [512][512] bf16
    const float* __restrict__ gamma,         // [32][512][512] f32
    const float* __restrict__ omega,         // [512][4]
    unsigned short* __restrict__ featb,      // [32][512][2048] bf16: sin dump (pre-g)
    float* __restrict__ msum) {              // [32][512][512] f32: sum_d theta
    extern __shared__ char smem[];
    unsigned short* sc_lds = (unsigned short*)smem;
    unsigned short* XT0 = (unsigned short*)(smem + 116480);
    unsigned short* XT1 = (unsigned short*)(smem + 133120);

    const int tid = threadIdx.x;
    const int w = tid >> 6, l = tid & 63;
    const int c = l & 15, q = l >> 4;
    const int h = (c >> 3) & 1, bl = (c >> 2) & 1, d = c & 3, bd = c & 7;
    const int bglob = (int)blockIdx.x;       // one batch per block
    const int roff = q * 4 + 2 * h + bl;     // lane's row offset within tile
    const int ieoff = q * 4 + 2 * h;         // even row of the lane's (bl) pair

    // ---- XT0 init: sin rows (0-7) = 0, cos rows (8-15) = 1.0bf16 ----
    for (int idx = tid; idx < 16 * 260; idx += 512)
        ((unsigned*)XT0)[idx] = (idx < 8 * 260) ? 0u : 0x3f803f80u;
    // ---- stage LDS sc tiles 16..22 (global rows 256..367) ----
    {
        const unsigned* g32 = (const unsigned*)scb;
        unsigned* l32 = (unsigned*)sc_lds;
        for (int it = 0; it < 56; ++it) {
            int idx = it * 512 + tid;
            int row = idx >> 8, col = idx & 255;
            l32[row * 260 + col] = g32[(256 + row) * 256 + col];
        }
    }
    // ---- AGPR-pinned tiles: rows [w*16,+16), [128+w*16,+16), [384+w*16,+16) ----
    short8_t at0[16], at1[16], at3[16];
    {
        const unsigned short* p0 = scb + (size_t)(w * 16 + c) * 512 + q * 8;
        const unsigned short* p1 = scb + (size_t)(128 + w * 16 + c) * 512 + q * 8;
        const unsigned short* p3 = scb + (size_t)(384 + w * 16 + c) * 512 + q * 8;
#pragma unroll
        for (int kk = 0; kk < 16; ++kk) {
            at0[kk] = *(const short8_t*)(p0 + kk * 32);
            at1[kk] = *(const short8_t*)(p1 + kk * 32);
            at3[kk] = *(const short8_t*)(p3 + kk * 32);
        }
    }
    const unsigned short* al2 = sc_lds + (w * 16 + c) * 520 + q * 8;               // w<7
    const unsigned short* gs2 = scb + (size_t)(256 + w * 16 + c) * 512 + q * 8;    // w==7

    float om[4], th[4], sn[4], cs[4];
#pragma unroll
    for (int mi = 0; mi < 4; ++mi) {
        int i = mi * 128 + w * 16 + roff;
        om[mi] = omega[i * 4 + d];
        th[mi] = 0.f; sn[mi] = 0.f; cs[mi] = 1.f;
    }
    __syncthreads();

    for (int t = 0; t < T_; ++t) {
        const unsigned short* bt = ((t & 1) ? XT1 : XT0) + c * 520 + q * 8;
        unsigned short* xw = (t & 1) ? XT0 : XT1;

        // gamma loads
        float gv[4];
        {
            const float* grow = gamma + ((size_t)bglob * 512 + t) * 512;
#pragma unroll
            for (int mi = 0; mi < 4; ++mi)
                gv[mi] = grow[mi * 128 + w * 16 + roff];
        }

        // MFMA coupling: 4 independent 16-deep chains; A from AGPR for tiles 0,1,3
        float4_t ac0 = {0.f, 0.f, 0.f, 0.f}, ac1 = {0.f, 0.f, 0.f, 0.f};
        float4_t ac2 = {0.f, 0.f, 0.f, 0.f}, ac3 = {0.f, 0.f, 0.f, 0.f};
        if (w < 7) {
#pragma unroll
            for (int kk = 0; kk < 16; ++kk) {
                short8_t bf = *(const short8_t*)(bt + kk * 32);
                short8_t a2 = *(const short8_t*)(al2 + kk * 32);
                MFMA_A(ac0, at0[kk], bf);
                MFMA_A(ac1, at1[kk], bf);
                MFMA_V(ac2, a2, bf);
                MFMA_A(ac3, at3[kk], bf);
            }
        } else {
#pragma unroll
            for (int kk = 0; kk < 16; ++kk) {
                short8_t bf = *(const short8_t*)(bt + kk * 32);
                short8_t a2 = *(const short8_t*)(gs2 + kk * 32);
                MFMA_A(ac0, at0[kk], bf);
                MFMA_A(ac1, at1[kk], bf);
                MFMA_V(ac2, a2, bf);
                MFMA_A(ac3, at3[kk], bf);
            }
        }
        // hazard insurance: inline-asm MFMA -> VALU read of acc (compiler can't see inside asm)
        asm volatile("s_nop 7\n\ts_nop 7");

        // combine st/ct halves (shfl 8), theta update, hw sincos
#pragma unroll
        for (int mi = 0; mi < 4; ++mi) {
            float4_t acc = mi == 0 ? ac0 : mi == 1 ? ac1 : mi == 2 ? ac2 : ac3;
            float oA = bl ? acc[1] : acc[0];
            float oB = bl ? acc[3] : acc[2];
            float own = h ? oB : oA;
            float send = h ? oA : oB;
            float recv = __shfl_xor(send, 8, 64);
            float Sst = h ? recv : own;
            float Sct = h ? own : recv;
            float coup = cs[mi] * Sst - sn[mi] * Sct;
            th[mi] += 0.1f * (om[mi] + gv[mi] + (1.f / 512.f) * coup);
            sn[mi] = sin_hw(th[mi]);
            cs[mi] = cos_hw(th[mi]);
        }

        // write new st/ct into XT[next]: pack row-pair via shfl_xor(4); rows bd and 8+bd
#pragma unroll
        for (int mi = 0; mi < 4; ++mi) {
            float psn = __shfl_xor(sn[mi], 4, 64);
            float pcs = __shfl_xor(cs[mi], 4, 64);
            float se = bl ? psn : sn[mi], so = bl ? sn[mi] : psn;
            float ce = bl ? pcs : cs[mi], co = bl ? cs[mi] : pcs;
            unsigned sp = f2bf(se) | (f2bf(so) << 16);
            unsigned cp = f2bf(ce) | (f2bf(co) << 16);
            int ib = mi * 128 + w * 16 + ieoff;
            ((unsigned*)xw)[(bd * 520 + ib) >> 1] = sp;
            ((unsigned*)xw)[((8 + bd) * 520 + ib) >> 1] = cp;
        }
        asm volatile("s_waitcnt lgkmcnt(0)" ::: "memory");
        __builtin_amdgcn_s_barrier();

        // ---- tail AFTER the barrier (registers + global only) ----
        {
            float m0 = th[0], m1 = th[1], m2 = th[2], m3 = th[3];
            m0 += __shfl_xor(m0, 1, 64); m0 += __shfl_xor(m0, 2, 64);
            m1 += __shfl_xor(m1, 1, 64); m1 += __shfl_xor(m1, 2, 64);
            m2 += __shfl_xor(m2, 1, 64); m2 += __shfl_xor(m2, 2, 64);
            m3 += __shfl_xor(m3, 1, 64); m3 += __shfl_xor(m3, 2, 64);
            float ms = (l & 2) ? ((l & 1) ? m3 : m2) : ((l & 1) ? m1 : m0);
            int i_own = (l & 3) * 128 + w * 16 + roff;
            msum[((size_t)bglob * 512 + t) * 512 + i_own] = ms;
        }
        {
            float A0 = sn[0], A1 = sn[1], A2 = sn[2], A3 = sn[3];
            bool bit0 = (l & 1), bit1 = (l & 2);
            float sA = __shfl_xor(bit0 ? A0 : A1, 1, 64);
            float sB = __shfl_xor(bit0 ? A2 : A3, 1, 64);
            float B0 = bit0 ? sA : A0;
            float B1 = bit0 ? A1 : sA;
            float B2 = bit0 ? sB : A2;
            float B3 = bit0 ? A3 : sB;
            float sC = __shfl_xor(bit1 ? B0 : B2, 2, 64);
            float sD = __shfl_xor(bit1 ? B1 : B3, 2, 64);
            float c0 = bit1 ? sC : B0;
            float c1 = bit1 ? sD : B1;
            float c2 = bit1 ? B2 : sC;
            float c3 = bit1 ? B3 : sD;
            uint2 pk;
            pk.x = f2bf(c0) | (f2bf(c1) << 16);
            pk.y = f2bf(c2) | (f2bf(c3) << 16);
            int i_own = (l & 3) * 128 + w * 16 + roff;
            *(uint2*)(featb + ((size_t)bglob * 512 + t) * 2048 + i_own * 4) = pk;
        }
    }
}

// ---------------- post: g from msum, featb *= g (in place), gb = bf16(g_t) ----------------
__global__ __launch_bounds__(256) void post_kernel(
    const float* __restrict__ msum,      // [32][512][512]
    unsigned short* __restrict__ featb,  // [32][512][2048] RMW
    unsigned short* __restrict__ gb) {   // [32][512][512]
    int idx = blockIdx.x * 256 + threadIdx.x;  // 8,388,608
    int i = idx & 511;
    int t = (idx >> 9) & 511;
    int b = idx >> 18;
    int t2 = t < 2 ? 0 : t - 2;
    float m2 = msum[((size_t)b * 512 + t2) * 512 + i];
    float g = 0.5f + 0.5f * sin_hw(m2 * 0.25f);
    uint2* fp = (uint2*)(featb + ((size_t)b * 512 + t) * 2048 + i * 4);
    uint2 v = *fp;
    float f0 = bf2f(v.x & 0xffffu) * g;
    float f1 = __uint_as_float(v.x & 0xffff0000u) * g;
    float f2 = bf2f(v.y & 0xffffu) * g;
    float f3 = __uint_as_float(v.y & 0xffff0000u) * g;
    v.x = f2bf(f0) | (f2bf(f1) << 16);
    v.y = f2bf(f2) | (f2bf(f3) << 16);
    *fp = v;
    float mt = msum[((size_t)b * 512 + t) * 512 + i];
    gb[((size_t)b * 512 + t) * 512 + i] =
        (unsigned short)f2bf(0.5f + 0.5f * sin_hw(mt * 0.25f));
}

// ---------------- LIF membrane scan: cur(f32) -> spike f32 (in place) + bf16 copy ----------------
__global__ __launch_bounds__(256) void mem_scan_kernel(
    float* __restrict__ io, unsigned short* __restrict__ spb) {
    int tid = blockIdx.x * 256 + threadIdx.x;  // 65536 = B*H
    int h = tid & (H_ - 1), b = tid >> 11;
    float mem = 0.f;
    float* base = io + (size_t)b * T_ * H_ + h;
    unsigned short* sb = spb + (size_t)b * T_ * H_ + h;
    for (int t = 0; t < T_; ++t) {
        float cur = base[(size_t)t * H_];
        mem = 0.5f * mem + cur;
        float sp = 1.f / (1.f + __expf(-4.f * (mem - 1.f)));
        mem -= sp;
        base[(size_t)t * H_] = sp;
        sb[(size_t)t * H_] = (unsigned short)f2bf(sp);
    }
}

// ---------------- conv1d(k=5,pad=2) over T + log_softmax over C ----------------
__global__ __launch_bounds__(128) void conv_lsm_kernel(
    const float* __restrict__ snn, const float* __restrict__ Wc,
    const float* __restrict__ bc, float* __restrict__ out0) {
    __shared__ float sl[36 * 128];
    const int b = blockIdx.x >> 4;
    const int tt0 = (blockIdx.x & 15) * 32;
    const int co = threadIdx.x;
    for (int r = 0; r < 36; ++r) {
        int t = tt0 + r - 2;
        sl[r * 128 + co] = (t >= 0 && t < T_) ? snn[(size_t)(b * T_ + t) * 128 + co] : 0.f;
    }
    __syncthreads();
    float acc[32];
#pragma unroll
    for (int i = 0; i < 32; ++i) acc[i] = 0.f;
    for (int ci = 0; ci < 128; ++ci) {
        const float* wp = &Wc[(size_t)(co * 128 + ci) * 5];
        float w0 = wp[0], w1 = wp[1], w2 = wp[2], w3 = wp[3], w4 = wp[4];
        const float* col = &sl[ci];
        float r0 = col[0 * 128], r1 = col[1 * 128], r2 = col[2 * 128], r3 = col[3 * 128];
#pragma unroll
        for (int i = 0; i < 32; ++i) {
            float r4 = col[(i + 4) * 128];
            acc[i] += w0 * r0 + w1 * r1 + w2 * r2 + w3 * r3 + w4 * r4;
            r0 = r1; r1 = r2; r2 = r3; r3 = r4;
        }
    }
    float bco = bc[co];
    __syncthreads();
    float* cl = sl;
#pragma unroll
    for (int i = 0; i < 32; ++i) cl[i * 129 + co] = acc[i] + bco;
    __syncthreads();
    if (co < 32) {
        int t = tt0 + co;
        float mx = -3.4e38f;
        for (int cc = 0; cc < 128; ++cc) mx = fmaxf(mx, cl[co * 129 + cc]);
        float se = 0.f;
        for (int cc = 0; cc < 128; ++cc) se += __expf(cl[co * 129 + cc] - mx);
        float lse = mx + __logf(se);
        for (int cc = 0; cc < 128; ++cc)
            out0[((size_t)(b * 128 + cc)) * T_ + t] = cl[co * 129 + cc] - lse;
    }
}

// ---------------- launch ----------------
extern "C" void kernel_launch(void* const* d_in, const int* in_sizes, int n_in,
                              void* d_out, int out_size, void* d_ws, size_t ws_size,
                              hipStream_t stream) {
    (void)in_sizes; (void)n_in; (void)out_size; (void)ws_size;
    const float* x      = (const float*)d_in[0];
    const float* sc     = (const float*)d_in[1];
    const float* W_proj = (const float*)d_in[2];
    const float* b_proj = (const float*)d_in[3];
    const float* ln_g   = (const float*)d_in[4];
    const float* ln_b   = (const float*)d_in[5];
    const float* W_enc  = (const float*)d_in[6];
    const float* b_enc  = (const float*)d_in[7];
    const float* omega  = (const float*)d_in[8];
    const float* W_mask = (const float*)d_in[9];
    const float* b_mask = (const float*)d_in[10];
    const float* W_in   = (const float*)d_in[11];
    const float* b_in   = (const float*)d_in[12];
    const float* W_out  = (const float*)d_in[13];
    const float* b_out  = (const float*)d_in[14];
    const float* W_conv = (const float*)d_in[15];
    const float* b_conv = (const float*)d_in[16];

    float* out0 = (float*)d_out;                   // [B,C,T]
    float* out1 = out0 + (size_t)B_ * C_ * T_;     // [B,T,H] f32: cur -> spikes

    const int M = B_ * T_;  // 16384
    char* w = (char*)d_ws;
    float*          gamma  = (float*)w;                         // @0          33,554,432
    unsigned short* featb  = (unsigned short*)(w + 33554432);   // @33.5M      67,108,864
    float*          msum   = (float*)(w + 100663296);           // @100.7M     33,554,432
    unsigned short* gb     = (unsigned short*)(w + 134217728);  // @134.2M     16,777,216
    unsigned short* scb    = (unsigned short*)(w + 150994944);  // @151.0M        524,288
    unsigned short* wprojT = (unsigned short*)(w + 151519232);  // [2048,512]   2,097,152
    unsigned short* wencT  = (unsigned short*)(w + 153616384);  // [512,2048]   2,097,152
    unsigned short* winT   = (unsigned short*)(w + 155713536);  // [2048,2048]  8,388,608
    unsigned short* woutT  = (unsigned short*)(w + 164102144);  // [128,2048]     524,288
    unsigned short* wmT    = (unsigned short*)(w + 164626432);  // [512,512]      524,288
    unsigned short* xb  = gb;      // alias: xb dead before post writes gb
    unsigned short* Zb  = featb;   // alias: Z dead before scan writes featb
    unsigned short* spb = featb;   // alias: featb dead after G3
    float* snn_pre = gamma;        // alias: gamma dead after scan

    // conversions
    cvt_bf16_kernel<<<512, 256, 0, stream>>>(sc, (unsigned*)scb, 131072);
    cvt_bf16_kernel<<<16384, 256, 0, stream>>>(x, (unsigned*)xb, 4194304);
    cvt_T_kernel<<<dim3(64, 16), 256, 0, stream>>>(W_proj, wprojT, 512, 2048);
    cvt_T_kernel<<<dim3(16, 64), 256, 0, stream>>>(W_enc, wencT, 2048, 512);
    cvt_T_kernel<<<dim3(64, 64), 256, 0, stream>>>(W_in, winT, 2048, 2048);
    cvt_T_kernel<<<dim3(4, 64), 256, 0, stream>>>(W_out, woutT, 2048, 128);
    cvt_T_kernel<<<dim3(16, 16), 256, 0, stream>>>(W_mask, wmT, 512, 512);

    // G1: Zb = bf16(x @ W_proj + b_proj)
    gemm_bf16<1, false><<<dim3(16, 128), 256, 0, stream>>>(xb, wprojT, b_proj, Zb, M, H_, N_);
    // LN + LeakyReLU in place (bf16)
    ln_leaky_kernel<<<M, 256, 0, stream>>>(Zb, ln_g, ln_b);
    // G2: gamma(f32) = Zb @ W_enc + b_enc
    gemm_bf16<0, false><<<dim3(4, 128), 256, 0, stream>>>(Zb, wencT, b_enc, gamma, M, N_, H_);
    // theta scan -> featb (sin dump), msum   [32 blocks: one batch per block]
    scan_kernel<<<32, 512, SCAN_LDS_BYTES, stream>>>(scb, gamma, omega, featb, msum);
    // post: featb *= g_{t-2}, gb = bf16(g(theta_t))
    post_kernel<<<32768, 256, 0, stream>>>(msum, featb, gb);
    // deferred mask: featb *= sigmoid(gb_shift @ W_mask + b_mask)
    gemm_bf16<2, true><<<dim3(4, 128), 256, 0, stream>>>(gb, wmT, b_mask, featb, M, N_, N_);
    // G3: cur(f32, out1) = featb @ W_in + b_in
    gemm_bf16<0, false><<<dim3(16, 128), 256, 0, stream>>>(featb, winT, b_in, out1, M, H_, N_ * D_);
    // LIF membrane scan in place + bf16 spikes
    mem_scan_kernel<<<256, 256, 0, stream>>>(out1, spb);
    // G4: snn_pre(f32) = spikes @ W_out + b_out
    gemm_bf16<0, false><<<dim3(1, 128), 256, 0, stream>>>(spb, woutT, b_out, snn_pre, M, C_, H_);
    // conv1d + log_softmax -> out0
    conv_lsm_kernel<<<dim3(B_ * 16), 128, 0, stream>>>(snn_pre, W_conv, b_conv, out0);
}

// Round 14
// 1565.944 us; speedup vs baseline: 1.6998x; 1.6998x over previous
//
#include <hip/hip_runtime.h>
#include <math.h>

// Problem constants
#define B_ 32
#define T_ 512
#define N_ 512
#define D_ 4
#define H_ 2048
#define C_ 128

typedef __attribute__((ext_vector_type(8))) short short8_t;
typedef __attribute__((ext_vector_type(4))) float float4_t;

// ---------------- helpers ----------------
__device__ __forceinline__ unsigned f2bf(float x) {
    unsigned u = __float_as_uint(x);
    return (u + 0x7fffu + ((u >> 16) & 1u)) >> 16;
}
__device__ __forceinline__ float bf2f(unsigned u) {
    return __uint_as_float(u << 16);
}
#define INV2PI 0.15915494309189535f
__device__ __forceinline__ float sin_hw(float x) {
    float r = x * INV2PI;
    r -= floorf(r);
    return __builtin_amdgcn_sinf(r);
}
__device__ __forceinline__ float cos_hw(float x) {
    float r = x * INV2PI;
    r -= floorf(r);
    return __builtin_amdgcn_cosf(r);
}

// ---------------- f32 -> bf16 straight convert (packed pairs) ----------------
__global__ __launch_bounds__(256) void cvt_bf16_kernel(
    const float* __restrict__ in, unsigned* __restrict__ out, int n2) {
    int i = blockIdx.x * 256 + threadIdx.x;
    if (i < n2) out[i] = f2bf(in[2 * i]) | (f2bf(in[2 * i + 1]) << 16);
}

// ---------------- sc f32 -> fp8 e4m3 (hw cvt, packed pairs) ----------------
__global__ __launch_bounds__(256) void cvt_sc8_kernel(
    const float* __restrict__ in, unsigned short* __restrict__ out) {
    int i = blockIdx.x * 256 + threadIdx.x;  // 131072 pairs
    int p = __builtin_amdgcn_cvt_pk_fp8_f32(in[2 * i], in[2 * i + 1], 0, false);
    out[i] = (unsigned short)p;
}

// ---------------- f32 [R,C] -> bf16 [C,R] transpose-convert ----------------
__global__ __launch_bounds__(256) void cvt_T_kernel(
    const float* __restrict__ in, unsigned short* __restrict__ out, int R, int C) {
    __shared__ float tl[32][33];
    const int tr = blockIdx.y * 32, tc = blockIdx.x * 32;
    const int a = threadIdx.x >> 3, b4 = (threadIdx.x & 7) * 4;
    float4 v = *(const float4*)(in + (size_t)(tr + a) * C + tc + b4);
    tl[a][b4] = v.x; tl[a][b4 + 1] = v.y; tl[a][b4 + 2] = v.z; tl[a][b4 + 3] = v.w;
    __syncthreads();
    unsigned* o32 = (unsigned*)out;
    size_t base = ((size_t)(tc + a) * R + tr + b4) >> 1;
    o32[base]     = f2bf(tl[b4][a])     | (f2bf(tl[b4 + 1][a]) << 16);
    o32[base + 1] = f2bf(tl[b4 + 2][a]) | (f2bf(tl[b4 + 3][a]) << 16);
}

// ---------------- bf16 MFMA GEMM: C[M,N] = A[M,K] @ BT[N,K]^T + bias ----------------
template <int EPI, bool AREMAP>
__global__ __launch_bounds__(256) void gemm_bf16(
    const unsigned short* __restrict__ A, const unsigned short* __restrict__ BT,
    const float* __restrict__ bias, void* __restrict__ Cout,
    int M, int N, int K) {
    __shared__ unsigned short Al[128 * 72];
    __shared__ unsigned short Bl[128 * 72];
    const int tid = threadIdx.x;
    const int wid = tid >> 6, l = tid & 63;
    const int c = l & 15, q = l >> 4;
    const int wr = wid >> 1, wc = wid & 1;
    const int m0 = blockIdx.y * 128, n0 = blockIdx.x * 128;
    float4_t acc[4][4];
#pragma unroll
    for (int i = 0; i < 4; ++i)
#pragma unroll
        for (int j = 0; j < 4; ++j) acc[i][j] = (float4_t){0.f, 0.f, 0.f, 0.f};

    const int sr = tid >> 1, sh = tid & 1;
    size_t a_row = (size_t)(m0 + sr);
    if (AREMAP) {
        int tt = (m0 + sr) & 511;
        a_row = (size_t)(((m0 + sr) & ~511) | (tt < 2 ? 0 : tt - 2));
    }
    const unsigned short* ag = A + a_row * K + sh * 32;
    const unsigned short* bg = BT + (size_t)(n0 + sr) * K + sh * 32;
    unsigned short* aw = Al + sr * 72 + sh * 32;
    unsigned short* bw = Bl + sr * 72 + sh * 32;

    for (int k0 = 0; k0 < K; k0 += 64) {
        uint4 av0 = *(const uint4*)(ag);
        uint4 av1 = *(const uint4*)(ag + 8);
        uint4 av2 = *(const uint4*)(ag + 16);
        uint4 av3 = *(const uint4*)(ag + 24);
        uint4 bv0 = *(const uint4*)(bg);
        uint4 bv1 = *(const uint4*)(bg + 8);
        uint4 bv2 = *(const uint4*)(bg + 16);
        uint4 bv3 = *(const uint4*)(bg + 24);
        __syncthreads();  // prior frag reads complete
        *(uint4*)(aw) = av0; *(uint4*)(aw + 8) = av1;
        *(uint4*)(aw + 16) = av2; *(uint4*)(aw + 24) = av3;
        *(uint4*)(bw) = bv0; *(uint4*)(bw + 8) = bv1;
        *(uint4*)(bw + 16) = bv2; *(uint4*)(bw + 24) = bv3;
        __syncthreads();
#pragma unroll
        for (int kk = 0; kk < 2; ++kk) {
            short8_t af[4], bf[4];
#pragma unroll
            for (int mt = 0; mt < 4; ++mt)
                af[mt] = *(const short8_t*)(Al + (wr * 64 + mt * 16 + c) * 72 + kk * 32 + q * 8);
#pragma unroll
            for (int nt = 0; nt < 4; ++nt)
                bf[nt] = *(const short8_t*)(Bl + (wc * 64 + nt * 16 + c) * 72 + kk * 32 + q * 8);
#pragma unroll
            for (int mt = 0; mt < 4; ++mt)
#pragma unroll
                for (int nt = 0; nt < 4; ++nt)
                    acc[mt][nt] = __builtin_amdgcn_mfma_f32_16x16x32_bf16(
                        af[mt], bf[nt], acc[mt][nt], 0, 0, 0);
        }
        ag += 64; bg += 64;
    }

#pragma unroll
    for (int mt = 0; mt < 4; ++mt) {
        int row = m0 + wr * 64 + mt * 16 + q * 4;
#pragma unroll
        for (int nt = 0; nt < 4; ++nt) {
            int col = n0 + wc * 64 + nt * 16 + c;
            float bs = bias[col];
            if (EPI == 0) {
                float* Cf = (float*)Cout;
#pragma unroll
                for (int r = 0; r < 4; ++r)
                    Cf[(size_t)(row + r) * N + col] = acc[mt][nt][r] + bs;
            } else if (EPI == 1) {
                unsigned short* Cb = (unsigned short*)Cout;
#pragma unroll
                for (int r = 0; r < 4; ++r)
                    Cb[(size_t)(row + r) * N + col] = (unsigned short)f2bf(acc[mt][nt][r] + bs);
            } else {
                unsigned short* Fb = (unsigned short*)Cout;
#pragma unroll
                for (int r = 0; r < 4; ++r) {
                    float s = 1.f / (1.f + __expf(-(acc[mt][nt][r] + bs)));
                    unsigned short* fp = Fb + (size_t)(row + r) * 2048 + col * 4;
                    unsigned u0 = *(const unsigned*)fp;
                    unsigned u1 = *(const unsigned*)(fp + 2);
                    float f0 = bf2f(u0 & 0xffffu) * s;
                    float f1 = __uint_as_float(u0 & 0xffff0000u) * s;
                    float f2 = bf2f(u1 & 0xffffu) * s;
                    float f3 = __uint_as_float(u1 & 0xffff0000u) * s;
                    *(unsigned*)fp = f2bf(f0) | (f2bf(f1) << 16);
                    *(unsigned*)(fp + 2) = f2bf(f2) | (f2bf(f3) << 16);
                }
            }
        }
    }
}

// ---------------- LayerNorm + LeakyReLU over bf16 rows of H=2048, in place ----------------
__device__ __forceinline__ float block_sum256(float v, float* red) {
#pragma unroll
    for (int o = 32; o > 0; o >>= 1) v += __shfl_down(v, o, 64);
    int w = threadIdx.x >> 6;
    if ((threadIdx.x & 63) == 0) red[w] = v;
    __syncthreads();
    float r = red[0] + red[1] + red[2] + red[3];
    __syncthreads();
    return r;
}

__global__ __launch_bounds__(256) void ln_leaky_kernel(
    unsigned short* __restrict__ Z, const float* __restrict__ gam,
    const float* __restrict__ bet) {
    __shared__ float red[4];
    unsigned short* zr = Z + (size_t)blockIdx.x * H_;
    const int tid = threadIdx.x;
    float v[8];
    float s = 0.f;
#pragma unroll
    for (int i = 0; i < 8; ++i) { v[i] = bf2f((unsigned)zr[tid + i * 256]); s += v[i]; }
    s = block_sum256(s, red);
    float mu = s * (1.f / H_);
    float qq = 0.f;
#pragma unroll
    for (int i = 0; i < 8; ++i) { float dd = v[i] - mu; qq += dd * dd; }
    qq = block_sum256(qq, red);
    float rs = rsqrtf(qq * (1.f / H_) + 1e-5f);
#pragma unroll
    for (int i = 0; i < 8; ++i) {
        int cc = tid + i * 256;
        float y = (v[i] - mu) * rs * gam[cc] + bet[cc];
        zr[cc] = (unsigned short)f2bf(y > 0.f ? y : 0.1f * y);
    }
}

// ---------------- theta-scan v11: fp8 coupling — fully resident sc ----------------
// 32 blocks x 512 threads, one batch per block (r12 separable layout, r12 step order).
// fp8 e4m3 halves every sc byte: tiles 0,1 in 64 VGPRs (fits the 128 budget ->
// TRUE residency), tiles 2,3 FULLY LDS-resident (256 rows x 520B = 133KB).
// Zero in-loop L2 sc traffic. XT8 (st/ct) in fp8 via hw v_cvt_pk_fp8_f32.
// mfma_f32_16x16x32_fp8_fp8: same 8-elem/lane fragment geometry as bf16, i64 operands.
#define SCAN_LDS_BYTES 149760
// LDS: sc_lds [256][520]u8 @0 (133120) ; XT0 @133120 (8320) ; XT1 @141440 (8320)

__global__ __launch_bounds__(512) __attribute__((amdgpu_waves_per_eu(2, 2)))
void scan_kernel(
    const unsigned char* __restrict__ scb8,  // [512][512] fp8 e4m3
    const float* __restrict__ gamma,         // [32][512][512] f32
    const float* __restrict__ omega,         // [512][4]
    unsigned short* __restrict__ featb,      // [32][512][2048] bf16: sin dump (pre-g)
    float* __restrict__ msum) {              // [32][512][512] f32: sum_d theta
    extern __shared__ char smem[];
    unsigned char* sc_lds = (unsigned char*)smem;
    unsigned char* XT0 = (unsigned char*)(smem + 133120);
    unsigned char* XT1 = (unsigned char*)(smem + 141440);

    const int tid = threadIdx.x;
    const int w = tid >> 6, l = tid & 63;
    const int c = l & 15, q = l >> 4;
    const int h = (c >> 3) & 1, bl = (c >> 2) & 1, d = c & 3, bd = c & 7;
    const int bglob = (int)blockIdx.x;       // one batch per block
    const int roff = q * 4 + 2 * h + bl;     // lane's row offset within tile
    const int ieoff = q * 4 + 2 * h;         // even row of the lane's (bl) pair

    // ---- XT0 init: sin rows (0-7) = fp8 0, cos rows (8-15) = fp8 1.0 (0x38) ----
    for (int idx = tid; idx < 2080; idx += 512)
        ((unsigned*)XT0)[idx] = (idx < 1040) ? 0u : 0x38383838u;
    // ---- stage LDS sc rows 256..511 (fp8), stride 520B ----
    {
        const unsigned* g32 = (const unsigned*)scb8;
        unsigned* l32 = (unsigned*)sc_lds;
#pragma unroll 4
        for (int it = 0; it < 64; ++it) {
            int idx = it * 512 + tid;
            int row = idx >> 7, col = idx & 127;
            l32[row * 130 + col] = g32[(256 + row) * 128 + col];
        }
    }
    // ---- register tiles (fp8, 32 VGPR each): rows [w*16,+16) and [128+w*16,+16) ----
    long at0[16], at1[16];
    {
        const unsigned char* p0 = scb8 + (size_t)(w * 16 + c) * 512 + q * 8;
        const unsigned char* p1 = scb8 + (size_t)(128 + w * 16 + c) * 512 + q * 8;
#pragma unroll
        for (int kk = 0; kk < 16; ++kk) {
            at0[kk] = *(const long*)(p0 + kk * 32);
            at1[kk] = *(const long*)(p1 + kk * 32);
        }
    }
    const unsigned char* lds2 = sc_lds + (w * 16 + c) * 520 + q * 8;          // rows 256..
    const unsigned char* lds3 = sc_lds + (128 + w * 16 + c) * 520 + q * 8;    // rows 384..

    float om[4], th[4], sn[4], cs[4];
#pragma unroll
    for (int mi = 0; mi < 4; ++mi) {
        int i = mi * 128 + w * 16 + roff;
        om[mi] = omega[i * 4 + d];
        th[mi] = 0.f; sn[mi] = 0.f; cs[mi] = 1.f;
    }
    __syncthreads();

    for (int t = 0; t < T_; ++t) {
        const unsigned char* bt = ((t & 1) ? XT1 : XT0) + c * 520 + q * 8;
        unsigned char* xw = (t & 1) ? XT0 : XT1;

        // gamma loads
        float gv[4];
        {
            const float* grow = gamma + ((size_t)bglob * 512 + t) * 512;
#pragma unroll
            for (int mi = 0; mi < 4; ++mi)
                gv[mi] = grow[mi * 128 + w * 16 + roff];
        }

        // MFMA coupling: 4 independent 16-deep fp8 chains (tiles 0,1 reg; 2,3 LDS)
        float4_t ac0 = {0.f, 0.f, 0.f, 0.f}, ac1 = {0.f, 0.f, 0.f, 0.f};
        float4_t ac2 = {0.f, 0.f, 0.f, 0.f}, ac3 = {0.f, 0.f, 0.f, 0.f};
#pragma unroll
        for (int kk = 0; kk < 16; ++kk) {
            long bfr = *(const long*)(bt + kk * 32);
            long a2 = *(const long*)(lds2 + kk * 32);
            long a3 = *(const long*)(lds3 + kk * 32);
            ac0 = __builtin_amdgcn_mfma_f32_16x16x32_fp8_fp8(at0[kk], bfr, ac0, 0, 0, 0);
            ac1 = __builtin_amdgcn_mfma_f32_16x16x32_fp8_fp8(at1[kk], bfr, ac1, 0, 0, 0);
            ac2 = __builtin_amdgcn_mfma_f32_16x16x32_fp8_fp8(a2, bfr, ac2, 0, 0, 0);
            ac3 = __builtin_amdgcn_mfma_f32_16x16x32_fp8_fp8(a3, bfr, ac3, 0, 0, 0);
        }

        // combine st/ct halves (shfl 8), theta update, hw sincos
#pragma unroll
        for (int mi = 0; mi < 4; ++mi) {
            float4_t acc = mi == 0 ? ac0 : mi == 1 ? ac1 : mi == 2 ? ac2 : ac3;
            float oA = bl ? acc[1] : acc[0];
            float oB = bl ? acc[3] : acc[2];
            float own = h ? oB : oA;
            float send = h ? oA : oB;
            float recv = __shfl_xor(send, 8, 64);
            float Sst = h ? recv : own;
            float Sct = h ? own : recv;
            float coup = cs[mi] * Sst - sn[mi] * Sct;
            th[mi] += 0.1f * (om[mi] + gv[mi] + (1.f / 512.f) * coup);
            sn[mi] = sin_hw(th[mi]);
            cs[mi] = cos_hw(th[mi]);
        }

        // write new st/ct into XT[next] as fp8: pack row-pair via shfl_xor(4)
#pragma unroll
        for (int mi = 0; mi < 4; ++mi) {
            float psn = __shfl_xor(sn[mi], 4, 64);
            float pcs = __shfl_xor(cs[mi], 4, 64);
            float se = bl ? psn : sn[mi], so = bl ? sn[mi] : psn;
            float ce = bl ? pcs : cs[mi], co = bl ? cs[mi] : pcs;
            int sp = __builtin_amdgcn_cvt_pk_fp8_f32(se, so, 0, false);
            int cp = __builtin_amdgcn_cvt_pk_fp8_f32(ce, co, 0, false);
            int ib = mi * 128 + w * 16 + ieoff;
            ((unsigned short*)xw)[(bd * 520 + ib) >> 1] = (unsigned short)sp;
            ((unsigned short*)xw)[((8 + bd) * 520 + ib) >> 1] = (unsigned short)cp;
        }
        asm volatile("s_waitcnt lgkmcnt(0)" ::: "memory");
        __builtin_amdgcn_s_barrier();

        // ---- tail AFTER the barrier (registers + global only) ----
        {
            float m0 = th[0], m1 = th[1], m2 = th[2], m3 = th[3];
            m0 += __shfl_xor(m0, 1, 64); m0 += __shfl_xor(m0, 2, 64);
            m1 += __shfl_xor(m1, 1, 64); m1 += __shfl_xor(m1, 2, 64);
            m2 += __shfl_xor(m2, 1, 64); m2 += __shfl_xor(m2, 2, 64);
            m3 += __shfl_xor(m3, 1, 64); m3 += __shfl_xor(m3, 2, 64);
            float ms = (l & 2) ? ((l & 1) ? m3 : m2) : ((l & 1) ? m1 : m0);
            int i_own = (l & 3) * 128 + w * 16 + roff;
            msum[((size_t)bglob * 512 + t) * 512 + i_own] = ms;
        }
        {
            float A0 = sn[0], A1 = sn[1], A2 = sn[2], A3 = sn[3];
            bool bit0 = (l & 1), bit1 = (l & 2);
            float sA = __shfl_xor(bit0 ? A0 : A1, 1, 64);
            float sB = __shfl_xor(bit0 ? A2 : A3, 1, 64);
            float B0 = bit0 ? sA : A0;
            float B1 = bit0 ? A1 : sA;
            float B2 = bit0 ? sB : A2;
            float B3 = bit0 ? A3 : sB;
            float sC = __shfl_xor(bit1 ? B0 : B2, 2, 64);
            float sD = __shfl_xor(bit1 ? B1 : B3, 2, 64);
            float c0 = bit1 ? sC : B0;
            float c1 = bit1 ? sD : B1;
            float c2 = bit1 ? B2 : sC;
            float c3 = bit1 ? B3 : sD;
            uint2 pk;
            pk.x = f2bf(c0) | (f2bf(c1) << 16);
            pk.y = f2bf(c2) | (f2bf(c3) << 16);
            int i_own = (l & 3) * 128 + w * 16 + roff;
            *(uint2*)(featb + ((size_t)bglob * 512 + t) * 2048 + i_own * 4) = pk;
        }
    }
}

// ---------------- post: g from msum, featb *= g (in place), gb = bf16(g_t) ----------------
__global__ __launch_bounds__(256) void post_kernel(
    const float* __restrict__ msum,      // [32][512][512]
    unsigned short* __restrict__ featb,  // [32][512][2048] RMW
    unsigned short* __restrict__ gb) {   // [32][512][512]
    int idx = blockIdx.x * 256 + threadIdx.x;  // 8,388,608
    int i = idx & 511;
    int t = (idx >> 9) & 511;
    int b = idx >> 18;
    int t2 = t < 2 ? 0 : t - 2;
    float m2 = msum[((size_t)b * 512 + t2) * 512 + i];
    float g = 0.5f + 0.5f * sin_hw(m2 * 0.25f);
    uint2* fp = (uint2*)(featb + ((size_t)b * 512 + t) * 2048 + i * 4);
    uint2 v = *fp;
    float f0 = bf2f(v.x & 0xffffu) * g;
    float f1 = __uint_as_float(v.x & 0xffff0000u) * g;
    float f2 = bf2f(v.y & 0xffffu) * g;
    float f3 = __uint_as_float(v.y & 0xffff0000u) * g;
    v.x = f2bf(f0) | (f2bf(f1) << 16);
    v.y = f2bf(f2) | (f2bf(f3) << 16);
    *fp = v;
    float mt = msum[((size_t)b * 512 + t) * 512 + i];
    gb[((size_t)b * 512 + t) * 512 + i] =
        (unsigned short)f2bf(0.5f + 0.5f * sin_hw(mt * 0.25f));
}

// ---------------- LIF membrane scan: cur(f32) -> spike f32 (in place) + bf16 copy ----------------
__global__ __launch_bounds__(256) void mem_scan_kernel(
    float* __restrict__ io, unsigned short* __restrict__ spb) {
    int tid = blockIdx.x * 256 + threadIdx.x;  // 65536 = B*H
    int h = tid & (H_ - 1), b = tid >> 11;
    float mem = 0.f;
    float* base = io + (size_t)b * T_ * H_ + h;
    unsigned short* sb = spb + (size_t)b * T_ * H_ + h;
    for (int t = 0; t < T_; ++t) {
        float cur = base[(size_t)t * H_];
        mem = 0.5f * mem + cur;
        float sp = 1.f / (1.f + __expf(-4.f * (mem - 1.f)));
        mem -= sp;
        base[(size_t)t * H_] = sp;
        sb[(size_t)t * H_] = (unsigned short)f2bf(sp);
    }
}

// ---------------- conv1d(k=5,pad=2) over T + log_softmax over C ----------------
__global__ __launch_bounds__(128) void conv_lsm_kernel(
    const float* __restrict__ snn, const float* __restrict__ Wc,
    const float* __restrict__ bc, float* __restrict__ out0) {
    __shared__ float sl[36 * 128];
    const int b = blockIdx.x >> 4;
    const int tt0 = (blockIdx.x & 15) * 32;
    const int co = threadIdx.x;
    for (int r = 0; r < 36; ++r) {
        int t = tt0 + r - 2;
        sl[r * 128 + co] = (t >= 0 && t < T_) ? snn[(size_t)(b * T_ + t) * 128 + co] : 0.f;
    }
    __syncthreads();
    float acc[32];
#pragma unroll
    for (int i = 0; i < 32; ++i) acc[i] = 0.f;
    for (int ci = 0; ci < 128; ++ci) {
        const float* wp = &Wc[(size_t)(co * 128 + ci) * 5];
        float w0 = wp[0], w1 = wp[1], w2 = wp[2], w3 = wp[3], w4 = wp[4];
        const float* col = &sl[ci];
        float r0 = col[0 * 128], r1 = col[1 * 128], r2 = col[2 * 128], r3 = col[3 * 128];
#pragma unroll
        for (int i = 0; i < 32; ++i) {
            float r4 = col[(i + 4) * 128];
            acc[i] += w0 * r0 + w1 * r1 + w2 * r2 + w3 * r3 + w4 * r4;
            r0 = r1; r1 = r2; r2 = r3; r3 = r4;
        }
    }
    float bco = bc[co];
    __syncthreads();
    float* cl = sl;
#pragma unroll
    for (int i = 0; i < 32; ++i) cl[i * 129 + co] = acc[i] + bco;
    __syncthreads();
    if (co < 32) {
        int t = tt0 + co;
        float mx = -3.4e38f;
        for (int cc = 0; cc < 128; ++cc) mx = fmaxf(mx, cl[co * 129 + cc]);
        float se = 0.f;
        for (int cc = 0; cc < 128; ++cc) se += __expf(cl[co * 129 + cc] - mx);
        float lse = mx + __logf(se);
        for (int cc = 0; cc < 128; ++cc)
            out0[((size_t)(b * 128 + cc)) * T_ + t] = cl[co * 129 + cc] - lse;
    }
}

// ---------------- launch ----------------
extern "C" void kernel_launch(void* const* d_in, const int* in_sizes, int n_in,
                              void* d_out, int out_size, void* d_ws, size_t ws_size,
                              hipStream_t stream) {
    (void)in_sizes; (void)n_in; (void)out_size; (void)ws_size;
    const float* x      = (const float*)d_in[0];
    const float* sc     = (const float*)d_in[1];
    const float* W_proj = (const float*)d_in[2];
    const float* b_proj = (const float*)d_in[3];
    const float* ln_g   = (const float*)d_in[4];
    const float* ln_b   = (const float*)d_in[5];
    const float* W_enc  = (const float*)d_in[6];
    const float* b_enc  = (const float*)d_in[7];
    const float* omega  = (const float*)d_in[8];
    const float* W_mask = (const float*)d_in[9];
    const float* b_mask = (const float*)d_in[10];
    const float* W_in   = (const float*)d_in[11];
    const float* b_in   = (const float*)d_in[12];
    const float* W_out  = (const float*)d_in[13];
    const float* b_out  = (const float*)d_in[14];
    const float* W_conv = (const float*)d_in[15];
    const float* b_conv = (const float*)d_in[16];

    float* out0 = (float*)d_out;                   // [B,C,T]
    float* out1 = out0 + (size_t)B_ * C_ * T_;     // [B,T,H] f32: cur -> spikes

    const int M = B_ * T_;  // 16384
    char* w = (char*)d_ws;
    float*          gamma  = (float*)w;                         // @0          33,554,432
    unsigned short* featb  = (unsigned short*)(w + 33554432);   // @33.5M      67,108,864
    float*          msum   = (float*)(w + 100663296);           // @100.7M     33,554,432
    unsigned short* gb     = (unsigned short*)(w + 134217728);  // @134.2M     16,777,216
    unsigned char*  scb8   = (unsigned char*)(w + 150994944);   // @151.0M        262,144
    unsigned short* wprojT = (unsigned short*)(w + 151519232);  // [2048,512]   2,097,152
    unsigned short* wencT  = (unsigned short*)(w + 153616384);  // [512,2048]   2,097,152
    unsigned short* winT   = (unsigned short*)(w + 155713536);  // [2048,2048]  8,388,608
    unsigned short* woutT  = (unsigned short*)(w + 164102144);  // [128,2048]     524,288
    unsigned short* wmT    = (unsigned short*)(w + 164626432);  // [512,512]      524,288
    unsigned short* xb  = gb;      // alias: xb dead before post writes gb
    unsigned short* Zb  = featb;   // alias: Z dead before scan writes featb
    unsigned short* spb = featb;   // alias: featb dead after G3
    float* snn_pre = gamma;        // alias: gamma dead after scan

    // conversions
    cvt_sc8_kernel<<<512, 256, 0, stream>>>(sc, (unsigned short*)scb8);
    cvt_bf16_kernel<<<16384, 256, 0, stream>>>(x, (unsigned*)xb, 4194304);
    cvt_T_kernel<<<dim3(64, 16), 256, 0, stream>>>(W_proj, wprojT, 512, 2048);
    cvt_T_kernel<<<dim3(16, 64), 256, 0, stream>>>(W_enc, wencT, 2048, 512);
    cvt_T_kernel<<<dim3(64, 64), 256, 0, stream>>>(W_in, winT, 2048, 2048);
    cvt_T_kernel<<<dim3(4, 64), 256, 0, stream>>>(W_out, woutT, 2048, 128);
    cvt_T_kernel<<<dim3(16, 16), 256, 0, stream>>>(W_mask, wmT, 512, 512);

    // G1: Zb = bf16(x @ W_proj + b_proj)
    gemm_bf16<1, false><<<dim3(16, 128), 256, 0, stream>>>(xb, wprojT, b_proj, Zb, M, H_, N_);
    // LN + LeakyReLU in place (bf16)
    ln_leaky_kernel<<<M, 256, 0, stream>>>(Zb, ln_g, ln_b);
    // G2: gamma(f32) = Zb @ W_enc + b_enc
    gemm_bf16<0, false><<<dim3(4, 128), 256, 0, stream>>>(Zb, wencT, b_enc, gamma, M, N_, H_);
    // theta scan -> featb (sin dump), msum   [32 blocks: one batch per block]
    scan_kernel<<<32, 512, SCAN_LDS_BYTES, stream>>>(scb8, gamma, omega, featb, msum);
    // post: featb *= g_{t-2}, gb = bf16(g(theta_t))
    post_kernel<<<32768, 256, 0, stream>>>(msum, featb, gb);
    // deferred mask: featb *= sigmoid(gb_shift @ W_mask + b_mask)
    gemm_bf16<2, true><<<dim3(4, 128), 256, 0, stream>>>(gb, wmT, b_mask, featb, M, N_, N_);
    // G3: cur(f32, out1) = featb @ W_in + b_in
    gemm_bf16<0, false><<<dim3(16, 128), 256, 0, stream>>>(featb, winT, b_in, out1, M, H_, N_ * D_);
    // LIF membrane scan in place + bf16 spikes
    mem_scan_kernel<<<256, 256, 0, stream>>>(out1, spb);
    // G4: snn_pre(f32) = spikes @ W_out + b_out
    gemm_bf16<0, false><<<dim3(1, 128), 256, 0, stream>>>(spb, woutT, b_out, snn_pre, M, C_, H_);
    // conv1d + log_softmax -> out0
    conv_lsm_kernel<<<dim3(B_ * 16), 128, 0, stream>>>(snn_pre, W_conv, b_conv, out0);
}

// Round 15
// 1561.500 us; speedup vs baseline: 1.7046x; 1.0028x over previous
//
#include <hip/hip_runtime.h>
#include <math.h>

// Problem constants
#define B_ 32
#define T_ 512
#define N_ 512
#define D_ 4
#define H_ 2048
#define C_ 128

typedef __attribute__((ext_vector_type(8))) short short8_t;
typedef __attribute__((ext_vector_type(4))) float float4_t;

// ---------------- helpers ----------------
__device__ __forceinline__ unsigned f2bf(float x) {
    unsigned u = __float_as_uint(x);
    return (u + 0x7fffu + ((u >> 16) & 1u)) >> 16;
}
__device__ __forceinline__ float bf2f(unsigned u) {
    return __uint_as_float(u << 16);
}
#define INV2PI 0.15915494309189535f
__device__ __forceinline__ float sin_hw(float x) {
    float r = x * INV2PI;
    r -= floorf(r);
    return __builtin_amdgcn_sinf(r);
}
__device__ __forceinline__ float cos_hw(float x) {
    float r = x * INV2PI;
    r -= floorf(r);
    return __builtin_amdgcn_cosf(r);
}

// ---------------- f32 -> bf16 straight convert (packed pairs) ----------------
__global__ __launch_bounds__(256) void cvt_bf16_kernel(
    const float* __restrict__ in, unsigned* __restrict__ out, int n2) {
    int i = blockIdx.x * 256 + threadIdx.x;
    if (i < n2) out[i] = f2bf(in[2 * i]) | (f2bf(in[2 * i + 1]) << 16);
}

// ---------------- sc f32 -> fp8 e4m3 (hw cvt, packed pairs) ----------------
__global__ __launch_bounds__(256) void cvt_sc8_kernel(
    const float* __restrict__ in, unsigned short* __restrict__ out) {
    int i = blockIdx.x * 256 + threadIdx.x;  // 131072 pairs
    int p = __builtin_amdgcn_cvt_pk_fp8_f32(in[2 * i], in[2 * i + 1], 0, false);
    out[i] = (unsigned short)p;
}

// ---------------- f32 [R,C] -> bf16 [C,R] transpose-convert ----------------
__global__ __launch_bounds__(256) void cvt_T_kernel(
    const float* __restrict__ in, unsigned short* __restrict__ out, int R, int C) {
    __shared__ float tl[32][33];
    const int tr = blockIdx.y * 32, tc = blockIdx.x * 32;
    const int a = threadIdx.x >> 3, b4 = (threadIdx.x & 7) * 4;
    float4 v = *(const float4*)(in + (size_t)(tr + a) * C + tc + b4);
    tl[a][b4] = v.x; tl[a][b4 + 1] = v.y; tl[a][b4 + 2] = v.z; tl[a][b4 + 3] = v.w;
    __syncthreads();
    unsigned* o32 = (unsigned*)out;
    size_t base = ((size_t)(tc + a) * R + tr + b4) >> 1;
    o32[base]     = f2bf(tl[b4][a])     | (f2bf(tl[b4 + 1][a]) << 16);
    o32[base + 1] = f2bf(tl[b4 + 2][a]) | (f2bf(tl[b4 + 3][a]) << 16);
}

// ---------------- bf16 MFMA GEMM: C[M,N] = A[M,K] @ BT[N,K]^T + bias ----------------
template <int EPI, bool AREMAP>
__global__ __launch_bounds__(256) void gemm_bf16(
    const unsigned short* __restrict__ A, const unsigned short* __restrict__ BT,
    const float* __restrict__ bias, void* __restrict__ Cout,
    int M, int N, int K) {
    __shared__ unsigned short Al[128 * 72];
    __shared__ unsigned short Bl[128 * 72];
    const int tid = threadIdx.x;
    const int wid = tid >> 6, l = tid & 63;
    const int c = l & 15, q = l >> 4;
    const int wr = wid >> 1, wc = wid & 1;
    const int m0 = blockIdx.y * 128, n0 = blockIdx.x * 128;
    float4_t acc[4][4];
#pragma unroll
    for (int i = 0; i < 4; ++i)
#pragma unroll
        for (int j = 0; j < 4; ++j) acc[i][j] = (float4_t){0.f, 0.f, 0.f, 0.f};

    const int sr = tid >> 1, sh = tid & 1;
    size_t a_row = (size_t)(m0 + sr);
    if (AREMAP) {
        int tt = (m0 + sr) & 511;
        a_row = (size_t)(((m0 + sr) & ~511) | (tt < 2 ? 0 : tt - 2));
    }
    const unsigned short* ag = A + a_row * K + sh * 32;
    const unsigned short* bg = BT + (size_t)(n0 + sr) * K + sh * 32;
    unsigned short* aw = Al + sr * 72 + sh * 32;
    unsigned short* bw = Bl + sr * 72 + sh * 32;

    for (int k0 = 0; k0 < K; k0 += 64) {
        uint4 av0 = *(const uint4*)(ag);
        uint4 av1 = *(const uint4*)(ag + 8);
        uint4 av2 = *(const uint4*)(ag + 16);
        uint4 av3 = *(const uint4*)(ag + 24);
        uint4 bv0 = *(const uint4*)(bg);
        uint4 bv1 = *(const uint4*)(bg + 8);
        uint4 bv2 = *(const uint4*)(bg + 16);
        uint4 bv3 = *(const uint4*)(bg + 24);
        __syncthreads();  // prior frag reads complete
        *(uint4*)(aw) = av0; *(uint4*)(aw + 8) = av1;
        *(uint4*)(aw + 16) = av2; *(uint4*)(aw + 24) = av3;
        *(uint4*)(bw) = bv0; *(uint4*)(bw + 8) = bv1;
        *(uint4*)(bw + 16) = bv2; *(uint4*)(bw + 24) = bv3;
        __syncthreads();
#pragma unroll
        for (int kk = 0; kk < 2; ++kk) {
            short8_t af[4], bf[4];
#pragma unroll
            for (int mt = 0; mt < 4; ++mt)
                af[mt] = *(const short8_t*)(Al + (wr * 64 + mt * 16 + c) * 72 + kk * 32 + q * 8);
#pragma unroll
            for (int nt = 0; nt < 4; ++nt)
                bf[nt] = *(const short8_t*)(Bl + (wc * 64 + nt * 16 + c) * 72 + kk * 32 + q * 8);
#pragma unroll
            for (int mt = 0; mt < 4; ++mt)
#pragma unroll
                for (int nt = 0; nt < 4; ++nt)
                    acc[mt][nt] = __builtin_amdgcn_mfma_f32_16x16x32_bf16(
                        af[mt], bf[nt], acc[mt][nt], 0, 0, 0);
        }
        ag += 64; bg += 64;
    }

#pragma unroll
    for (int mt = 0; mt < 4; ++mt) {
        int row = m0 + wr * 64 + mt * 16 + q * 4;
#pragma unroll
        for (int nt = 0; nt < 4; ++nt) {
            int col = n0 + wc * 64 + nt * 16 + c;
            float bs = bias[col];
            if (EPI == 0) {
                float* Cf = (float*)Cout;
#pragma unroll
                for (int r = 0; r < 4; ++r)
                    Cf[(size_t)(row + r) * N + col] = acc[mt][nt][r] + bs;
            } else if (EPI == 1) {
                unsigned short* Cb = (unsigned short*)Cout;
#pragma unroll
                for (int r = 0; r < 4; ++r)
                    Cb[(size_t)(row + r) * N + col] = (unsigned short)f2bf(acc[mt][nt][r] + bs);
            } else {
                unsigned short* Fb = (unsigned short*)Cout;
#pragma unroll
                for (int r = 0; r < 4; ++r) {
                    float s = 1.f / (1.f + __expf(-(acc[mt][nt][r] + bs)));
                    unsigned short* fp = Fb + (size_t)(row + r) * 2048 + col * 4;
                    unsigned u0 = *(const unsigned*)fp;
                    unsigned u1 = *(const unsigned*)(fp + 2);
                    float f0 = bf2f(u0 & 0xffffu) * s;
                    float f1 = __uint_as_float(u0 & 0xffff0000u) * s;
                    float f2 = bf2f(u1 & 0xffffu) * s;
                    float f3 = __uint_as_float(u1 & 0xffff0000u) * s;
                    *(unsigned*)fp = f2bf(f0) | (f2bf(f1) << 16);
                    *(unsigned*)(fp + 2) = f2bf(f2) | (f2bf(f3) << 16);
                }
            }
        }
    }
}

// ---------------- LayerNorm + LeakyReLU over bf16 rows of H=2048, in place ----------------
__device__ __forceinline__ float block_sum256(float v, float* red) {
#pragma unroll
    for (int o = 32; o > 0; o >>= 1) v += __shfl_down(v, o, 64);
    int w = threadIdx.x >> 6;
    if ((threadIdx.x & 63) == 0) red[w] = v;
    __syncthreads();
    float r = red[0] + red[1] + red[2] + red[3];
    __syncthreads();
    return r;
}

__global__ __launch_bounds__(256) void ln_leaky_kernel(
    unsigned short* __restrict__ Z, const float* __restrict__ gam,
    const float* __restrict__ bet) {
    __shared__ float red[4];
    unsigned short* zr = Z + (size_t)blockIdx.x * H_;
    const int tid = threadIdx.x;
    float v[8];
    float s = 0.f;
#pragma unroll
    for (int i = 0; i < 8; ++i) { v[i] = bf2f((unsigned)zr[tid + i * 256]); s += v[i]; }
    s = block_sum256(s, red);
    float mu = s * (1.f / H_);
    float qq = 0.f;
#pragma unroll
    for (int i = 0; i < 8; ++i) { float dd = v[i] - mu; qq += dd * dd; }
    qq = block_sum256(qq, red);
    float rs = rsqrtf(qq * (1.f / H_) + 1e-5f);
#pragma unroll
    for (int i = 0; i < 8; ++i) {
        int cc = tid + i * 256;
        float y = (v[i] - mu) * rs * gam[cc] + bet[cc];
        zr[cc] = (unsigned short)f2bf(y > 0.f ? y : 0.1f * y);
    }
}

// ---------------- theta-scan v12: fp8, tiles 0,1,2 in registers, tile 3 in LDS ----------------
// 32 blocks x 512 threads, one batch per block. fp8 e4m3 coupling (r14-proven).
// at0,at1,at2 = 96 VGPRs of sc data (+~24 state ~= 120, under the observed 128
// allocation ceiling). Tile 3 (rows 384-511) LDS-resident. In-loop LDS sc traffic
// halves vs r14 (131KB -> 65KB sc + 65KB XT per CU-step).
#define SCAN_LDS_BYTES 83200
// LDS: sc_lds [128][520]u8 @0 (66560) ; XT0 @66560 (8320) ; XT1 @74880 (8320)

__global__ __launch_bounds__(512) __attribute__((amdgpu_waves_per_eu(2, 2)))
void scan_kernel(
    const unsigned char* __restrict__ scb8,  // [512][512] fp8 e4m3
    const float* __restrict__ gamma,         // [32][512][512] f32
    const float* __restrict__ omega,         // [512][4]
    unsigned short* __restrict__ featb,      // [32][512][2048] bf16: sin dump (pre-g)
    float* __restrict__ msum) {              // [32][512][512] f32: sum_d theta
    extern __shared__ char smem[];
    unsigned char* sc_lds = (unsigned char*)smem;
    unsigned char* XT0 = (unsigned char*)(smem + 66560);
    unsigned char* XT1 = (unsigned char*)(smem + 74880);

    const int tid = threadIdx.x;
    const int w = tid >> 6, l = tid & 63;
    const int c = l & 15, q = l >> 4;
    const int h = (c >> 3) & 1, bl = (c >> 2) & 1, d = c & 3, bd = c & 7;
    const int bglob = (int)blockIdx.x;       // one batch per block
    const int roff = q * 4 + 2 * h + bl;     // lane's row offset within tile
    const int ieoff = q * 4 + 2 * h;         // even row of the lane's (bl) pair

    // ---- XT0 init: sin rows (0-7) = fp8 0, cos rows (8-15) = fp8 1.0 (0x38) ----
    for (int idx = tid; idx < 2080; idx += 512)
        ((unsigned*)XT0)[idx] = (idx < 1040) ? 0u : 0x38383838u;
    // ---- stage LDS sc rows 384..511 (fp8), stride 520B ----
    {
        const unsigned* g32 = (const unsigned*)scb8;
        unsigned* l32 = (unsigned*)sc_lds;
#pragma unroll 4
        for (int it = 0; it < 32; ++it) {
            int idx = it * 512 + tid;
            int row = idx >> 7, col = idx & 127;
            l32[row * 130 + col] = g32[(384 + row) * 128 + col];
        }
    }
    // ---- register tiles (fp8, 32 VGPR each): rows [w*16,+16), [128+..], [256+..] ----
    long at0[16], at1[16], at2[16];
    {
        const unsigned char* p0 = scb8 + (size_t)(w * 16 + c) * 512 + q * 8;
        const unsigned char* p1 = scb8 + (size_t)(128 + w * 16 + c) * 512 + q * 8;
        const unsigned char* p2 = scb8 + (size_t)(256 + w * 16 + c) * 512 + q * 8;
#pragma unroll
        for (int kk = 0; kk < 16; ++kk) {
            at0[kk] = *(const long*)(p0 + kk * 32);
            at1[kk] = *(const long*)(p1 + kk * 32);
            at2[kk] = *(const long*)(p2 + kk * 32);
        }
    }
    const unsigned char* lds3 = sc_lds + (w * 16 + c) * 520 + q * 8;  // rows 384..

    float om[4], th[4], sn[4], cs[4];
#pragma unroll
    for (int mi = 0; mi < 4; ++mi) {
        int i = mi * 128 + w * 16 + roff;
        om[mi] = omega[i * 4 + d];
        th[mi] = 0.f; sn[mi] = 0.f; cs[mi] = 1.f;
    }
    __syncthreads();

    for (int t = 0; t < T_; ++t) {
        const unsigned char* bt = ((t & 1) ? XT1 : XT0) + c * 520 + q * 8;
        unsigned char* xw = (t & 1) ? XT0 : XT1;

        // gamma loads
        float gv[4];
        {
            const float* grow = gamma + ((size_t)bglob * 512 + t) * 512;
#pragma unroll
            for (int mi = 0; mi < 4; ++mi)
                gv[mi] = grow[mi * 128 + w * 16 + roff];
        }

        // MFMA coupling: 4 independent 16-deep fp8 chains (tiles 0,1,2 reg; 3 LDS)
        float4_t ac0 = {0.f, 0.f, 0.f, 0.f}, ac1 = {0.f, 0.f, 0.f, 0.f};
        float4_t ac2 = {0.f, 0.f, 0.f, 0.f}, ac3 = {0.f, 0.f, 0.f, 0.f};
#pragma unroll
        for (int kk = 0; kk < 16; ++kk) {
            long bfr = *(const long*)(bt + kk * 32);
            long a3 = *(const long*)(lds3 + kk * 32);
            ac0 = __builtin_amdgcn_mfma_f32_16x16x32_fp8_fp8(at0[kk], bfr, ac0, 0, 0, 0);
            ac1 = __builtin_amdgcn_mfma_f32_16x16x32_fp8_fp8(at1[kk], bfr, ac1, 0, 0, 0);
            ac2 = __builtin_amdgcn_mfma_f32_16x16x32_fp8_fp8(at2[kk], bfr, ac2, 0, 0, 0);
            ac3 = __builtin_amdgcn_mfma_f32_16x16x32_fp8_fp8(a3, bfr, ac3, 0, 0, 0);
        }

        // combine st/ct halves (shfl 8), theta update, hw sincos
#pragma unroll
        for (int mi = 0; mi < 4; ++mi) {
            float4_t acc = mi == 0 ? ac0 : mi == 1 ? ac1 : mi == 2 ? ac2 : ac3;
            float oA = bl ? acc[1] : acc[0];
            float oB = bl ? acc[3] : acc[2];
            float own = h ? oB : oA;
            float send = h ? oA : oB;
            float recv = __shfl_xor(send, 8, 64);
            float Sst = h ? recv : own;
            float Sct = h ? own : recv;
            float coup = cs[mi] * Sst - sn[mi] * Sct;
            th[mi] += 0.1f * (om[mi] + gv[mi] + (1.f / 512.f) * coup);
            sn[mi] = sin_hw(th[mi]);
            cs[mi] = cos_hw(th[mi]);
        }

        // write new st/ct into XT[next] as fp8: pack row-pair via shfl_xor(4)
#pragma unroll
        for (int mi = 0; mi < 4; ++mi) {
            float psn = __shfl_xor(sn[mi], 4, 64);
            float pcs = __shfl_xor(cs[mi], 4, 64);
            float se = bl ? psn : sn[mi], so = bl ? sn[mi] : psn;
            float ce = bl ? pcs : cs[mi], co = bl ? cs[mi] : pcs;
            int sp = __builtin_amdgcn_cvt_pk_fp8_f32(se, so, 0, false);
            int cp = __builtin_amdgcn_cvt_pk_fp8_f32(ce, co, 0, false);
            int ib = mi * 128 + w * 16 + ieoff;
            ((unsigned short*)xw)[(bd * 520 + ib) >> 1] = (unsigned short)sp;
            ((unsigned short*)xw)[((8 + bd) * 520 + ib) >> 1] = (unsigned short)cp;
        }
        asm volatile("s_waitcnt lgkmcnt(0)" ::: "memory");
        __builtin_amdgcn_s_barrier();

        // ---- tail AFTER the barrier (registers + global only) ----
        {
            float m0 = th[0], m1 = th[1], m2 = th[2], m3 = th[3];
            m0 += __shfl_xor(m0, 1, 64); m0 += __shfl_xor(m0, 2, 64);
            m1 += __shfl_xor(m1, 1, 64); m1 += __shfl_xor(m1, 2, 64);
            m2 += __shfl_xor(m2, 1, 64); m2 += __shfl_xor(m2, 2, 64);
            m3 += __shfl_xor(m3, 1, 64); m3 += __shfl_xor(m3, 2, 64);
            float ms = (l & 2) ? ((l & 1) ? m3 : m2) : ((l & 1) ? m1 : m0);
            int i_own = (l & 3) * 128 + w * 16 + roff;
            msum[((size_t)bglob * 512 + t) * 512 + i_own] = ms;
        }
        {
            float A0 = sn[0], A1 = sn[1], A2 = sn[2], A3 = sn[3];
            bool bit0 = (l & 1), bit1 = (l & 2);
            float sA = __shfl_xor(bit0 ? A0 : A1, 1, 64);
            float sB = __shfl_xor(bit0 ? A2 : A3, 1, 64);
            float B0 = bit0 ? sA : A0;
            float B1 = bit0 ? A1 : sA;
            float B2 = bit0 ? sB : A2;
            float B3 = bit0 ? A3 : sB;
            float sC = __shfl_xor(bit1 ? B0 : B2, 2, 64);
            float sD = __shfl_xor(bit1 ? B1 : B3, 2, 64);
            float c0 = bit1 ? sC : B0;
            float c1 = bit1 ? sD : B1;
            float c2 = bit1 ? B2 : sC;
            float c3 = bit1 ? B3 : sD;
            uint2 pk;
            pk.x = f2bf(c0) | (f2bf(c1) << 16);
            pk.y = f2bf(c2) | (f2bf(c3) << 16);
            int i_own = (l & 3) * 128 + w * 16 + roff;
            *(uint2*)(featb + ((size_t)bglob * 512 + t) * 2048 + i_own * 4) = pk;
        }
    }
}

// ---------------- post: g from msum, featb *= g (in place), gb = bf16(g_t) ----------------
__global__ __launch_bounds__(256) void post_kernel(
    const float* __restrict__ msum,      // [32][512][512]
    unsigned short* __restrict__ featb,  // [32][512][2048] RMW
    unsigned short* __restrict__ gb) {   // [32][512][512]
    int idx = blockIdx.x * 256 + threadIdx.x;  // 8,388,608
    int i = idx & 511;
    int t = (idx >> 9) & 511;
    int b = idx >> 18;
    int t2 = t < 2 ? 0 : t - 2;
    float m2 = msum[((size_t)b * 512 + t2) * 512 + i];
    float g = 0.5f + 0.5f * sin_hw(m2 * 0.25f);
    uint2* fp = (uint2*)(featb + ((size_t)b * 512 + t) * 2048 + i * 4);
    uint2 v = *fp;
    float f0 = bf2f(v.x & 0xffffu) * g;
    float f1 = __uint_as_float(v.x & 0xffff0000u) * g;
    float f2 = bf2f(v.y & 0xffffu) * g;
    float f3 = __uint_as_float(v.y & 0xffff0000u) * g;
    v.x = f2bf(f0) | (f2bf(f1) << 16);
    v.y = f2bf(f2) | (f2bf(f3) << 16);
    *fp = v;
    float mt = msum[((size_t)b * 512 + t) * 512 + i];
    gb[((size_t)b * 512 + t) * 512 + i] =
        (unsigned short)f2bf(0.5f + 0.5f * sin_hw(mt * 0.25f));
}

// ---------------- LIF membrane scan: cur(f32) -> spike f32 (in place) + bf16 copy ----------------
__global__ __launch_bounds__(256) void mem_scan_kernel(
    float* __restrict__ io, unsigned short* __restrict__ spb) {
    int tid = blockIdx.x * 256 + threadIdx.x;  // 65536 = B*H
    int h = tid & (H_ - 1), b = tid >> 11;
    float mem = 0.f;
    float* base = io + (size_t)b * T_ * H_ + h;
    unsigned short* sb = spb + (size_t)b * T_ * H_ + h;
    for (int t = 0; t < T_; ++t) {
        float cur = base[(size_t)t * H_];
        mem = 0.5f * mem + cur;
        float sp = 1.f / (1.f + __expf(-4.f * (mem - 1.f)));
        mem -= sp;
        base[(size_t)t * H_] = sp;
        sb[(size_t)t * H_] = (unsigned short)f2bf(sp);
    }
}

// ---------------- conv1d(k=5,pad=2) over T + log_softmax over C ----------------
__global__ __launch_bounds__(128) void conv_lsm_kernel(
    const float* __restrict__ snn, const float* __restrict__ Wc,
    const float* __restrict__ bc, float* __restrict__ out0) {
    __shared__ float sl[36 * 128];
    const int b = blockIdx.x >> 4;
    const int tt0 = (blockIdx.x & 15) * 32;
    const int co = threadIdx.x;
    for (int r = 0; r < 36; ++r) {
        int t = tt0 + r - 2;
        sl[r * 128 + co] = (t >= 0 && t < T_) ? snn[(size_t)(b * T_ + t) * 128 + co] : 0.f;
    }
    __syncthreads();
    float acc[32];
#pragma unroll
    for (int i = 0; i < 32; ++i) acc[i] = 0.f;
    for (int ci = 0; ci < 128; ++ci) {
        const float* wp = &Wc[(size_t)(co * 128 + ci) * 5];
        float w0 = wp[0], w1 = wp[1], w2 = wp[2], w3 = wp[3], w4 = wp[4];
        const float* col = &sl[ci];
        float r0 = col[0 * 128], r1 = col[1 * 128], r2 = col[2 * 128], r3 = col[3 * 128];
#pragma unroll
        for (int i = 0; i < 32; ++i) {
            float r4 = col[(i + 4) * 128];
            acc[i] += w0 * r0 + w1 * r1 + w2 * r2 + w3 * r3 + w4 * r4;
            r0 = r1; r1 = r2; r2 = r3; r3 = r4;
        }
    }
    float bco = bc[co];
    __syncthreads();
    float* cl = sl;
#pragma unroll
    for (int i = 0; i < 32; ++i) cl[i * 129 + co] = acc[i] + bco;
    __syncthreads();
    if (co < 32) {
        int t = tt0 + co;
        float mx = -3.4e38f;
        for (int cc = 0; cc < 128; ++cc) mx = fmaxf(mx, cl[co * 129 + cc]);
        float se = 0.f;
        for (int cc = 0; cc < 128; ++cc) se += __expf(cl[co * 129 + cc] - mx);
        float lse = mx + __logf(se);
        for (int cc = 0; cc < 128; ++cc)
            out0[((size_t)(b * 128 + cc)) * T_ + t] = cl[co * 129 + cc] - lse;
    }
}

// ---------------- launch ----------------
extern "C" void kernel_launch(void* const* d_in, const int* in_sizes, int n_in,
                              void* d_out, int out_size, void* d_ws, size_t ws_size,
                              hipStream_t stream) {
    (void)in_sizes; (void)n_in; (void)out_size; (void)ws_size;
    const float* x      = (const float*)d_in[0];
    const float* sc     = (const float*)d_in[1];
    const float* W_proj = (const float*)d_in[2];
    const float* b_proj = (const float*)d_in[3];
    const float* ln_g   = (const float*)d_in[4];
    const float* ln_b   = (const float*)d_in[5];
    const float* W_enc  = (const float*)d_in[6];
    const float* b_enc  = (const float*)d_in[7];
    const float* omega  = (const float*)d_in[8];
    const float* W_mask = (const float*)d_in[9];
    const float* b_mask = (const float*)d_in[10];
    const float* W_in   = (const float*)d_in[11];
    const float* b_in   = (const float*)d_in[12];
    const float* W_out  = (const float*)d_in[13];
    const float* b_out  = (const float*)d_in[14];
    const float* W_conv = (const float*)d_in[15];
    const float* b_conv = (const float*)d_in[16];

    float* out0 = (float*)d_out;                   // [B,C,T]
    float* out1 = out0 + (size_t)B_ * C_ * T_;     // [B,T,H] f32: cur -> spikes

    const int M = B_ * T_;  // 16384
    char* w = (char*)d_ws;
    float*          gamma  = (float*)w;                         // @0          33,554,432
    unsigned short* featb  = (unsigned short*)(w + 33554432);   // @33.5M      67,108,864
    float*          msum   = (float*)(w + 100663296);           // @100.7M     33,554,432
    unsigned short* gb     = (unsigned short*)(w + 134217728);  // @134.2M     16,777,216
    unsigned char*  scb8   = (unsigned char*)(w + 150994944);   // @151.0M        262,144
    unsigned short* wprojT = (unsigned short*)(w + 151519232);  // [2048,512]   2,097,152
    unsigned short* wencT  = (unsigned short*)(w + 153616384);  // [512,2048]   2,097,152
    unsigned short* winT   = (unsigned short*)(w + 155713536);  // [2048,2048]  8,388,608
    unsigned short* woutT  = (unsigned short*)(w + 164102144);  // [128,2048]     524,288
    unsigned short* wmT    = (unsigned short*)(w + 164626432);  // [512,512]      524,288
    unsigned short* xb  = gb;      // alias: xb dead before post writes gb
    unsigned short* Zb  = featb;   // alias: Z dead before scan writes featb
    unsigned short* spb = featb;   // alias: featb dead after G3
    float* snn_pre = gamma;        // alias: gamma dead after scan

    // conversions
    cvt_sc8_kernel<<<512, 256, 0, stream>>>(sc, (unsigned short*)scb8);
    cvt_bf16_kernel<<<16384, 256, 0, stream>>>(x, (unsigned*)xb, 4194304);
    cvt_T_kernel<<<dim3(64, 16), 256, 0, stream>>>(W_proj, wprojT, 512, 2048);
    cvt_T_kernel<<<dim3(16, 64), 256, 0, stream>>>(W_enc, wencT, 2048, 512);
    cvt_T_kernel<<<dim3(64, 64), 256, 0, stream>>>(W_in, winT, 2048, 2048);
    cvt_T_kernel<<<dim3(4, 64), 256, 0, stream>>>(W_out, woutT, 2048, 128);
    cvt_T_kernel<<<dim3(16, 16), 256, 0, stream>>>(W_mask, wmT, 512, 512);

    // G1: Zb = bf16(x @ W_proj + b_proj)
    gemm_bf16<1, false><<<dim3(16, 128), 256, 0, stream>>>(xb, wprojT, b_proj, Zb, M, H_, N_);
    // LN + LeakyReLU in place (bf16)
    ln_leaky_kernel<<<M, 256, 0, stream>>>(Zb, ln_g, ln_b);
    // G2: gamma(f32) = Zb @ W_enc + b_enc
    gemm_bf16<0, false><<<dim3(4, 128), 256, 0, stream>>>(Zb, wencT, b_enc, gamma, M, N_, H_);
    // theta scan -> featb (sin dump), msum   [32 blocks: one batch per block]
    scan_kernel<<<32, 512, SCAN_LDS_BYTES, stream>>>(scb8, gamma, omega, featb, msum);
    // post: featb *= g_{t-2}, gb = bf16(g(theta_t))
    post_kernel<<<32768, 256, 0, stream>>>(msum, featb, gb);
    // deferred mask: featb *= sigmoid(gb_shift @ W_mask + b_mask)
    gemm_bf16<2, true><<<dim3(4, 128), 256, 0, stream>>>(gb, wmT, b_mask, featb, M, N_, N_);
    // G3: cur(f32, out1) = featb @ W_in + b_in
    gemm_bf16<0, false><<<dim3(16, 128), 256, 0, stream>>>(featb, winT, b_in, out1, M, H_, N_ * D_);
    // LIF membrane scan in place + bf16 spikes
    mem_scan_kernel<<<256, 256, 0, stream>>>(out1, spb);
    // G4: snn_pre(f32) = spikes @ W_out + b_out
    gemm_bf16<0, false><<<dim3(1, 128), 256, 0, stream>>>(spb, woutT, b_out, snn_pre, M, C_, H_);
    // conv1d + log_softmax -> out0
    conv_lsm_kernel<<<dim3(B_ * 16), 128, 0, stream>>>(snn_pre, W_conv, b_conv, out0);
}